// Round 7
// baseline (946.562 us; speedup 1.0000x reference)
//
#include <hip/hip_runtime.h>

typedef __attribute__((ext_vector_type(8))) short bf16x8;
typedef __attribute__((ext_vector_type(4))) float f32x4;

constexpr int NB = 16;    // bases
constexpr int REFF = 9;   // relations

struct alignas(8) EPair { float v; int c; };

__device__ __forceinline__ unsigned short f2bf(float f) {
  unsigned u = __float_as_uint(f);
  u += 0x7FFFu + ((u >> 16) & 1u);          // round-to-nearest-even
  return (unsigned short)(u >> 16);
}
__device__ __forceinline__ float bf2f(short s) {
  return __uint_as_float(((unsigned)(unsigned short)s) << 16);
}

// ---------------- dual histogram: deg1 over g=r*N+dst, deg2 over dst ----------------
__global__ void hist_both_kernel(const int* __restrict__ rows,
                                 int* __restrict__ deg1, int* __restrict__ deg2,
                                 int E, int N) {
  int e = blockIdx.x * 256 + threadIdx.x;
  if (e >= E) return;
  int g = rows[e];
  atomicAdd(&deg1[g], 1);
  atomicAdd(&deg2[g % N], 1);
}

// ---------------- merged scan kernels (both CSRs in one launch) ----------------
__global__ void scan1_both(const int* __restrict__ deg1, int* __restrict__ bsum1,
                           int NR1, int NT1,
                           const int* __restrict__ deg2, int* __restrict__ bsum2,
                           int NR2) {
  const int* deg; int* bsum; int NR, b;
  if ((int)blockIdx.x < NT1) { deg = deg1; bsum = bsum1; NR = NR1; b = blockIdx.x; }
  else { deg = deg2; bsum = bsum2; NR = NR2; b = blockIdx.x - NT1; }
  __shared__ int s[256];
  int t = threadIdx.x;
  int base = b * 1024 + t * 4;
  int acc = 0;
#pragma unroll
  for (int q = 0; q < 4; ++q)
    if (base + q < NR) acc += deg[base + q];
  s[t] = acc;
  __syncthreads();
  for (int off = 128; off > 0; off >>= 1) {
    if (t < off) s[t] += s[t + off];
    __syncthreads();
  }
  if (t == 0) bsum[b] = s[0];
}

__global__ void scan2_both(int* __restrict__ bsum1, int* __restrict__ ptr1,
                           int NT1, int NR1,
                           int* __restrict__ bsum2, int* __restrict__ ptr2,
                           int NT2, int NR2) {
  int* bsum; int* ptr; int NT, NR;
  if (blockIdx.x == 0) { bsum = bsum1; ptr = ptr1; NT = NT1; NR = NR1; }
  else { bsum = bsum2; ptr = ptr2; NT = NT2; NR = NR2; }
  __shared__ int s[512];
  int t = threadIdx.x;
  int v = (t < NT) ? bsum[t] : 0;
  s[t] = v;
  __syncthreads();
  for (int off = 1; off < 512; off <<= 1) {
    int x = (t >= off) ? s[t - off] : 0;
    __syncthreads();
    s[t] += x;
    __syncthreads();
  }
  if (t < NT) bsum[t] = s[t] - v;
  if (t == NT - 1) ptr[NR] = s[t];
}

__global__ void scan3_both(const int* __restrict__ deg1, const int* __restrict__ bsum1,
                           int* __restrict__ ptr1, int NR1, int NT1,
                           const int* __restrict__ deg2, const int* __restrict__ bsum2,
                           int* __restrict__ ptr2, int NR2) {
  const int* deg; const int* bsum; int* ptr; int NR, b;
  if ((int)blockIdx.x < NT1) { deg = deg1; bsum = bsum1; ptr = ptr1; NR = NR1; b = blockIdx.x; }
  else { deg = deg2; bsum = bsum2; ptr = ptr2; NR = NR2; b = blockIdx.x - NT1; }
  __shared__ int s[256];
  int t = threadIdx.x;
  int base = b * 1024 + t * 4;
  int d[4];
#pragma unroll
  for (int q = 0; q < 4; ++q)
    d[q] = (base + q < NR) ? deg[base + q] : 0;
  int tsum = d[0] + d[1] + d[2] + d[3];
  s[t] = tsum;
  __syncthreads();
  for (int off = 1; off < 256; off <<= 1) {
    int x = (t >= off) ? s[t - off] : 0;
    __syncthreads();
    s[t] += x;
    __syncthreads();
  }
  int off0 = bsum[b] + s[t] - tsum;
#pragma unroll
  for (int q = 0; q < 4; ++q) {
    if (base + q < NR) ptr[base + q] = off0;
    off0 += d[q];
  }
}

// fill both CSRs; pay1.c packs rr=dst&31 in high bits
__global__ void fill_both_kernel(const int* __restrict__ rows,
                                 const int* __restrict__ cols,
                                 const float* __restrict__ vals,
                                 int* __restrict__ deg1, const int* __restrict__ ptr1,
                                 EPair* __restrict__ pay1,
                                 int* __restrict__ deg2, const int* __restrict__ ptr2,
                                 EPair* __restrict__ pay2, int E, int N) {
  int e = blockIdx.x * 256 + threadIdx.x;
  if (e >= E) return;
  int g = rows[e];
  int src = cols[e];
  float v = vals[e];
  int dst = g % N;
  int o1 = atomicSub(&deg1[g], 1);
  EPair p1v; p1v.v = v; p1v.c = src | ((dst & 31) << 20);
  pay1[ptr1[g] + o1 - 1] = p1v;
  int o2 = atomicSub(&deg2[dst], 1);
  EPair p2v; p2v.v = v; p2v.c = g - dst + src;   // r*N + src (row into Y2)
  pay2[ptr2[dst] + o2 - 1] = p2v;
}

// ---------------- merged prep: features->bf16 (column-permuted), pack W1, W2 ----------------
// Xbf storage: pos p holds true col c(p) = (p&7)*32 + (p>>3)   [p(c) = (c&31)*8 + (c>>5)]
__device__ __forceinline__ unsigned short pack_w_one(const float* __restrict__ comps,
                                                     const float* __restrict__ bases,
                                                     int idx, int NTI, int NTOT) {
  int j = idx & 7;
  int lane = (idx >> 3) & 63;
  int ni = (idx >> 9) % NTI;
  int t = (idx >> 9) / NTI;        // r*8 + ks
  int ks = t & 7;
  int r = t >> 3;
  int k = ks * 32 + ((lane >> 4) << 3) + j;
  int n = ni * 16 + (lane & 15);
  float acc = 0.f;
#pragma unroll
  for (int b = 0; b < NB; ++b)
    acc += comps[r * NB + b] * bases[(size_t)b * 256 * NTOT + (size_t)k * NTOT + n];
  return f2bf(acc);
}

__global__ void prep_kernel(const float* __restrict__ features,
                            unsigned short* __restrict__ Xbf,
                            const float* __restrict__ comps1,
                            const float* __restrict__ bases1,
                            unsigned short* __restrict__ W1p,
                            const float* __restrict__ comps2,
                            const float* __restrict__ bases2,
                            unsigned short* __restrict__ W2p, int N) {
  const int n8 = N * 32;                 // Xbf units of 8 shorts
  const int PW1 = REFF * 8 * 16 * 512;   // 589824
  const int PW2 = REFF * 8 * 2 * 512;    // 73728
  int idx = blockIdx.x * 256 + threadIdx.x;
  if (idx < n8) {
    int row = idx >> 5, t8 = idx & 31;
    const float* f = features + (size_t)row * 256 + t8;
    bf16x8 o;
#pragma unroll
    for (int j = 0; j < 8; ++j) o[j] = (short)f2bf(f[j * 32]);
    *reinterpret_cast<bf16x8*>(Xbf + (size_t)row * 256 + t8 * 8) = o;
  } else if (idx < n8 + PW1) {
    int i = idx - n8;
    W1p[i] = pack_w_one(comps1, bases1, i, 16, 256);
  } else if (idx < n8 + PW1 + PW2) {
    int i = idx - n8 - PW1;
    W2p[i] = pack_w_one(comps2, bases2, i, 2, 32);
  }
}

// ---------------- fused layer 1 (+ layer-2 transform): Y2 = relu(bias1 + sum_r A_r X W1_r) @ W2 ----------------
// 512 threads / 8 waves; 32-row node tile; edge-parallel LDS-atomic gather
__global__ __launch_bounds__(512, 8)
void fused_l1(const EPair* __restrict__ pay1, const int* __restrict__ ptr1,
              const unsigned short* __restrict__ Xbf,
              const unsigned short* __restrict__ W1p,
              const float* __restrict__ bias1,
              const unsigned short* __restrict__ W2p,
              unsigned short* __restrict__ Y2, int N) {
  __shared__ float tile[32 * 256];   // 32 KB f32 tile; low 16 KB reused as bf16 tile
  const int tid = threadIdx.x;
  const int w = tid >> 6, lane = tid & 63;
  const int unit = tid >> 5, cl = tid & 31;   // half-wave id / lane-in-half
  const int node0 = blockIdx.x * 32;
  const int nrows = (N - node0 < 32) ? (N - node0) : 32;
  char* lds = reinterpret_cast<char*>(tile);

  f32x4 acc[2][2];
#pragma unroll
  for (int mi = 0; mi < 2; ++mi)
#pragma unroll
    for (int ni = 0; ni < 2; ++ni) acc[mi][ni] = (f32x4)(0.f);

  for (int r = 0; r < REFF; ++r) {
    // zero f32 tile
    {
      float4 z = make_float4(0.f, 0.f, 0.f, 0.f);
      float4* zp = reinterpret_cast<float4*>(tile) + tid * 4;
      zp[0] = z; zp[1] = z; zp[2] = z; zp[3] = z;
    }
    __syncthreads();
    // edge-parallel accumulate: half-wave per edge, stride 16
    {
      int g0 = r * N + node0;
      int s0 = ptr1[g0];
      int s1 = ptr1[g0 + nrows];
      for (int i = s0 + unit; i < s1; i += 16) {
        EPair e = pay1[i];
        int src = e.c & 0xFFFFF;
        int rr = e.c >> 20;
        bf16x8 x = *reinterpret_cast<const bf16x8*>(Xbf + (size_t)src * 256 + cl * 8);
        int rb = rr * 1024;
        int sw = (rr & 7) << 5;
#pragma unroll
        for (int j = 0; j < 8; ++j) {     // x[j] = true col cl + j*32 -> bank cl
          int boff = (rb + (cl + j * 32) * 4) ^ sw;
          atomicAdd(reinterpret_cast<float*>(lds + boff), e.v * bf2f(x[j]));
        }
      }
    }
    __syncthreads();
    // convert f32 tile -> bf16 tile (in place, via regs)
    float4 c4[4];
    {
      int row = tid >> 4, t16 = tid & 15;
      int swf = (row & 7) << 5;
#pragma unroll
      for (int k = 0; k < 4; ++k) {
        int b = (row * 1024 + k * 256 + t16 * 16) ^ swf;
        c4[k] = *reinterpret_cast<const float4*>(lds + b);
      }
    }
    __syncthreads();
    {
      int row = tid >> 4, t16 = tid & 15;
      int swb = (row & 7) << 4;
#pragma unroll
      for (int k = 0; k < 4; ++k) {
        uint2 o;
        o.x = (unsigned)f2bf(c4[k].x) | ((unsigned)f2bf(c4[k].y) << 16);
        o.y = (unsigned)f2bf(c4[k].z) | ((unsigned)f2bf(c4[k].w) << 16);
        int b = (row * 512 + k * 128 + t16 * 8) ^ swb;
        *reinterpret_cast<uint2*>(lds + b) = o;
      }
    }
    __syncthreads();
    // MFMA phase (R6-proven bf16 tile layout)
#pragma unroll 2
    for (int ks = 0; ks < 8; ++ks) {
      bf16x8 a[2];
#pragma unroll
      for (int mi = 0; mi < 2; ++mi) {
        int row = mi * 16 + (lane & 15);
        int boff = (row * 512 + ks * 64 + ((lane >> 4) << 4)) ^ ((row & 7) << 4);
        a[mi] = *reinterpret_cast<const bf16x8*>(lds + boff);
      }
#pragma unroll
      for (int ni = 0; ni < 2; ++ni) {
        int niG = w * 2 + ni;
        bf16x8 b = *reinterpret_cast<const bf16x8*>(
            W1p + (((size_t)(r * 8 + ks) * 16 + niG) << 9) + lane * 8);
#pragma unroll
        for (int mi = 0; mi < 2; ++mi)
          acc[mi][ni] = __builtin_amdgcn_mfma_f32_16x16x32_bf16(a[mi], b,
                                                               acc[mi][ni], 0, 0, 0);
      }
    }
    __syncthreads();
  }

  // epilogue: out1 tile = bf16(relu(acc + bias1)) -> LDS bf16 tile
#pragma unroll
  for (int mi = 0; mi < 2; ++mi) {
#pragma unroll
    for (int ni = 0; ni < 2; ++ni) {
      int col = (w * 2 + ni) * 16 + (lane & 15);
      float bb = bias1[col];
#pragma unroll
      for (int reg = 0; reg < 4; ++reg) {
        int row = mi * 16 + ((lane >> 4) << 2) + reg;
        float v = fmaxf(acc[mi][ni][reg] + bb, 0.f);
        int b = (row * 512 + col * 2) ^ ((row & 7) << 4);
        *reinterpret_cast<unsigned short*>(lds + b) = f2bf(v);
      }
    }
  }
  __syncthreads();

  // layer-2 transform: Y2[r'] tile = out1_tile @ W2_{r'}; jobs j = (r', nj)
  for (int j = w; j < 18; j += 8) {
    int rp = j >> 1, nj = j & 1;
    f32x4 a2[2];
    a2[0] = (f32x4)(0.f); a2[1] = (f32x4)(0.f);
#pragma unroll
    for (int ks = 0; ks < 8; ++ks) {
      bf16x8 b = *reinterpret_cast<const bf16x8*>(
          W2p + (((size_t)(rp * 8 + ks) * 2 + nj) << 9) + lane * 8);
#pragma unroll
      for (int mi = 0; mi < 2; ++mi) {
        int row = mi * 16 + (lane & 15);
        int boff = (row * 512 + ks * 64 + ((lane >> 4) << 4)) ^ ((row & 7) << 4);
        bf16x8 a = *reinterpret_cast<const bf16x8*>(lds + boff);
        a2[mi] = __builtin_amdgcn_mfma_f32_16x16x32_bf16(a, b, a2[mi], 0, 0, 0);
      }
    }
    int col = nj * 16 + (lane & 15);
#pragma unroll
    for (int mi = 0; mi < 2; ++mi)
#pragma unroll
      for (int reg = 0; reg < 4; ++reg) {
        int row = node0 + mi * 16 + ((lane >> 4) << 2) + reg;
        if (row < N)
          Y2[((size_t)rp * N + row) * 32 + col] = f2bf(a2[mi][reg]);
      }
  }
}

// ---------------- layer 2 gather: wave per node, 4 edges in flight ----------------
__global__ __launch_bounds__(512, 8)
void gather_out_kernel(const EPair* __restrict__ pay2,
                       const int* __restrict__ ptr2,
                       const unsigned short* __restrict__ Y2,
                       const float* __restrict__ bias2,
                       float* __restrict__ out, int N) {
  int wv = threadIdx.x >> 6;
  int lane = threadIdx.x & 63;
  int qw = lane >> 4, c = lane & 15;
  int n = blockIdx.x * 8 + wv;
  if (n >= N) return;
  int p0 = ptr2[n], p1 = ptr2[n + 1];
  float ax = 0.f, ay = 0.f;
  for (int p = p0 + qw; p < p1; p += 4) {
    EPair cur = pay2[p];
    unsigned u = *reinterpret_cast<const unsigned*>(Y2 + (size_t)cur.c * 32 + c * 2);
    ax += cur.v * __uint_as_float(u << 16);
    ay += cur.v * __uint_as_float(u & 0xFFFF0000u);
  }
  ax += __shfl_xor(ax, 16); ay += __shfl_xor(ay, 16);
  ax += __shfl_xor(ax, 32); ay += __shfl_xor(ay, 32);
  if (lane < 16) {
    float2 o;
    o.x = ax + bias2[c * 2];
    o.y = ay + bias2[c * 2 + 1];
    reinterpret_cast<float2*>(out)[(size_t)n * 16 + c] = o;
  }
}

extern "C" void kernel_launch(void* const* d_in, const int* in_sizes, int n_in,
                              void* d_out, int out_size, void* d_ws, size_t ws_size,
                              hipStream_t stream) {
  const float* features = (const float*)d_in[0];
  const float* ver_vals = (const float*)d_in[1];
  const float* comps1   = (const float*)d_in[2];
  const float* bases1   = (const float*)d_in[3];
  const float* comps2   = (const float*)d_in[4];
  const float* bases2   = (const float*)d_in[5];
  const float* bias1    = (const float*)d_in[6];
  const float* bias2    = (const float*)d_in[7];
  const int* ver_rows   = (const int*)d_in[8];
  const int* ver_cols   = (const int*)d_in[9];

  const int N = in_sizes[0] / 256;   // 30000
  const int E = in_sizes[1];         // 500000
  const int NR = REFF * N;           // 270000
  const int NT1 = (NR + 1023) / 1024;
  const int NT2 = (N + 1023) / 1024;

  // ---- workspace layout (~44 MB; 64.1 MB proven-safe) ----
  char* p = (char*)d_ws;
  unsigned short* Xbf = (unsigned short*)p; p += (size_t)N * 256 * 2;        // 15.36 MB
  unsigned short* Y2  = (unsigned short*)p; p += (size_t)REFF * N * 32 * 2;  // 17.28 MB
  unsigned short* W1p = (unsigned short*)p; p += (size_t)REFF * 65536 * 2;   // 1.18 MB
  unsigned short* W2p = (unsigned short*)p; p += (size_t)REFF * 8192 * 2;    // 0.15 MB
  int* ptr1 = (int*)p;     p += (size_t)(NR + 4) * 4;
  int* ptr2 = (int*)p;     p += (size_t)(N + 4) * 4;
  EPair* pay1 = (EPair*)p; p += (size_t)E * 8;
  EPair* pay2 = (EPair*)p; p += (size_t)E * 8;
  int* deg1 = (int*)p;     p += (size_t)NR * 4;   // deg1+deg2 contiguous: one memset
  int* deg2 = (int*)p;     p += (size_t)N * 4;
  int* bsum1 = (int*)p;    p += 512 * 4;
  int* bsum2 = (int*)p;    p += 512 * 4;

  // ---- CSR build (both keys) ----
  hipMemsetAsync(deg1, 0, (size_t)(NR + N) * 4, stream);
  hist_both_kernel<<<(E + 255) / 256, 256, 0, stream>>>(ver_rows, deg1, deg2, E, N);
  scan1_both<<<NT1 + NT2, 256, 0, stream>>>(deg1, bsum1, NR, NT1, deg2, bsum2, N);
  scan2_both<<<2, 512, 0, stream>>>(bsum1, ptr1, NT1, NR, bsum2, ptr2, NT2, N);
  scan3_both<<<NT1 + NT2, 256, 0, stream>>>(deg1, bsum1, ptr1, NR, NT1,
                                            deg2, bsum2, ptr2, N);
  fill_both_kernel<<<(E + 255) / 256, 256, 0, stream>>>(
      ver_rows, ver_cols, ver_vals, deg1, ptr1, pay1, deg2, ptr2, pay2, E, N);

  // ---- prep: permuted Xbf + packed weights ----
  const int prep_total = N * 32 + REFF * 8 * 16 * 512 + REFF * 8 * 2 * 512;
  prep_kernel<<<(prep_total + 255) / 256, 256, 0, stream>>>(
      features, Xbf, comps1, bases1, W1p, comps2, bases2, W2p, N);

  // ---- fused layer 1 + layer-2 transform ----
  fused_l1<<<(N + 31) / 32, 512, 0, stream>>>(pay1, ptr1, Xbf, W1p, bias1,
                                              W2p, Y2, N);
  // ---- layer 2 gather ----
  gather_out_kernel<<<(N + 7) / 8, 512, 0, stream>>>(pay2, ptr2, Y2, bias2,
                                                     (float*)d_out, N);
}

// Round 8
// 260.061 us; speedup vs baseline: 3.6398x; 3.6398x over previous
//
#include <hip/hip_runtime.h>

typedef __attribute__((ext_vector_type(8))) short bf16x8;
typedef __attribute__((ext_vector_type(4))) float f32x4;

constexpr int NB = 16;    // bases
constexpr int REFF = 9;   // relations

struct alignas(8) EPair { float v; int c; };

__device__ __forceinline__ unsigned short f2bf(float f) {
  unsigned u = __float_as_uint(f);
  u += 0x7FFFu + ((u >> 16) & 1u);          // round-to-nearest-even
  return (unsigned short)(u >> 16);
}
__device__ __forceinline__ float bf2f(short s) {
  return __uint_as_float(((unsigned)(unsigned short)s) << 16);
}

// ---------------- dual histogram: deg1 over g=r*N+dst, deg2 over dst ----------------
__global__ void hist_both_kernel(const int* __restrict__ rows,
                                 int* __restrict__ deg1, int* __restrict__ deg2,
                                 int E, int N) {
  int e = blockIdx.x * 256 + threadIdx.x;
  if (e >= E) return;
  int g = rows[e];
  atomicAdd(&deg1[g], 1);
  atomicAdd(&deg2[g % N], 1);
}

// ---------------- merged scan kernels (both CSRs in one launch) ----------------
__global__ void scan1_both(const int* __restrict__ deg1, int* __restrict__ bsum1,
                           int NR1, int NT1,
                           const int* __restrict__ deg2, int* __restrict__ bsum2,
                           int NR2) {
  const int* deg; int* bsum; int NR, b;
  if ((int)blockIdx.x < NT1) { deg = deg1; bsum = bsum1; NR = NR1; b = blockIdx.x; }
  else { deg = deg2; bsum = bsum2; NR = NR2; b = blockIdx.x - NT1; }
  __shared__ int s[256];
  int t = threadIdx.x;
  int base = b * 1024 + t * 4;
  int acc = 0;
#pragma unroll
  for (int q = 0; q < 4; ++q)
    if (base + q < NR) acc += deg[base + q];
  s[t] = acc;
  __syncthreads();
  for (int off = 128; off > 0; off >>= 1) {
    if (t < off) s[t] += s[t + off];
    __syncthreads();
  }
  if (t == 0) bsum[b] = s[0];
}

__global__ void scan2_both(int* __restrict__ bsum1, int* __restrict__ ptr1,
                           int NT1, int NR1,
                           int* __restrict__ bsum2, int* __restrict__ ptr2,
                           int NT2, int NR2) {
  int* bsum; int* ptr; int NT, NR;
  if (blockIdx.x == 0) { bsum = bsum1; ptr = ptr1; NT = NT1; NR = NR1; }
  else { bsum = bsum2; ptr = ptr2; NT = NT2; NR = NR2; }
  __shared__ int s[512];
  int t = threadIdx.x;
  int v = (t < NT) ? bsum[t] : 0;
  s[t] = v;
  __syncthreads();
  for (int off = 1; off < 512; off <<= 1) {
    int x = (t >= off) ? s[t - off] : 0;
    __syncthreads();
    s[t] += x;
    __syncthreads();
  }
  if (t < NT) bsum[t] = s[t] - v;
  if (t == NT - 1) ptr[NR] = s[t];
}

__global__ void scan3_both(const int* __restrict__ deg1, const int* __restrict__ bsum1,
                           int* __restrict__ ptr1, int NR1, int NT1,
                           const int* __restrict__ deg2, const int* __restrict__ bsum2,
                           int* __restrict__ ptr2, int NR2) {
  const int* deg; const int* bsum; int* ptr; int NR, b;
  if ((int)blockIdx.x < NT1) { deg = deg1; bsum = bsum1; ptr = ptr1; NR = NR1; b = blockIdx.x; }
  else { deg = deg2; bsum = bsum2; ptr = ptr2; NR = NR2; b = blockIdx.x - NT1; }
  __shared__ int s[256];
  int t = threadIdx.x;
  int base = b * 1024 + t * 4;
  int d[4];
#pragma unroll
  for (int q = 0; q < 4; ++q)
    d[q] = (base + q < NR) ? deg[base + q] : 0;
  int tsum = d[0] + d[1] + d[2] + d[3];
  s[t] = tsum;
  __syncthreads();
  for (int off = 1; off < 256; off <<= 1) {
    int x = (t >= off) ? s[t - off] : 0;
    __syncthreads();
    s[t] += x;
    __syncthreads();
  }
  int off0 = bsum[b] + s[t] - tsum;
#pragma unroll
  for (int q = 0; q < 4; ++q) {
    if (base + q < NR) ptr[base + q] = off0;
    off0 += d[q];
  }
}

// fill both CSRs with inline (val, col) payloads; deg arrays consumed as cursors
__global__ void fill_both_kernel(const int* __restrict__ rows,
                                 const int* __restrict__ cols,
                                 const float* __restrict__ vals,
                                 int* __restrict__ deg1, const int* __restrict__ ptr1,
                                 EPair* __restrict__ pay1,
                                 int* __restrict__ deg2, const int* __restrict__ ptr2,
                                 EPair* __restrict__ pay2, int E, int N) {
  int e = blockIdx.x * 256 + threadIdx.x;
  if (e >= E) return;
  int g = rows[e];
  int src = cols[e];
  float v = vals[e];
  int o1 = atomicSub(&deg1[g], 1);
  EPair p1v; p1v.v = v; p1v.c = src;
  pay1[ptr1[g] + o1 - 1] = p1v;
  int dst = g % N;
  int o2 = atomicSub(&deg2[dst], 1);
  EPair p2v; p2v.v = v; p2v.c = g - dst + src;   // r*N + src (row into Y2)
  pay2[ptr2[dst] + o2 - 1] = p2v;
}

// ---------------- merged prep: features->bf16, pack W1, pack W2 ----------------
__device__ __forceinline__ unsigned short pack_w_one(const float* __restrict__ comps,
                                                     const float* __restrict__ bases,
                                                     int idx, int NTI, int NTOT) {
  int j = idx & 7;
  int lane = (idx >> 3) & 63;
  int ni = (idx >> 9) % NTI;
  int t = (idx >> 9) / NTI;        // r*8 + ks
  int ks = t & 7;
  int r = t >> 3;
  int k = ks * 32 + ((lane >> 4) << 3) + j;
  int n = ni * 16 + (lane & 15);
  float acc = 0.f;
#pragma unroll
  for (int b = 0; b < NB; ++b)
    acc += comps[r * NB + b] * bases[(size_t)b * 256 * NTOT + (size_t)k * NTOT + n];
  return f2bf(acc);
}

__global__ void prep_kernel(const float* __restrict__ features,
                            unsigned short* __restrict__ Xbf,
                            const float* __restrict__ comps1,
                            const float* __restrict__ bases1,
                            unsigned short* __restrict__ W1p,
                            const float* __restrict__ comps2,
                            const float* __restrict__ bases2,
                            unsigned short* __restrict__ W2p, int N) {
  const int n4 = N * 64;
  const int PW1 = REFF * 8 * 16 * 512;   // 589824
  const int PW2 = REFF * 8 * 2 * 512;    // 73728
  int idx = blockIdx.x * 256 + threadIdx.x;
  if (idx < n4) {
    float4 f = reinterpret_cast<const float4*>(features)[idx];
    ushort4 o;
    o.x = f2bf(f.x); o.y = f2bf(f.y); o.z = f2bf(f.z); o.w = f2bf(f.w);
    reinterpret_cast<ushort4*>(Xbf)[idx] = o;
  } else if (idx < n4 + PW1) {
    int i = idx - n4;
    W1p[i] = pack_w_one(comps1, bases1, i, 16, 256);
  } else if (idx < n4 + PW1 + PW2) {
    int i = idx - n4 - PW1;
    W2p[i] = pack_w_one(comps2, bases2, i, 2, 32);
  }
}

// ---------------- gather: half-wave owns a whole row (512B) — R6-proven ----------------
__device__ __forceinline__ void gather_rows_bf(const EPair* __restrict__ pay,
                                               const int* __restrict__ ptr,
                                               const unsigned short* __restrict__ Xbf,
                                               unsigned short* lds,
                                               int node0, int N, int r,
                                               int unit, int cl) {
#pragma unroll
  for (int q = 0; q < 2; ++q) {
    int rr = unit * 2 + q;              // row within 32-row tile
    int node = node0 + rr;
    float acc[8];
#pragma unroll
    for (int j = 0; j < 8; ++j) acc[j] = 0.f;
    if (node < N) {
      int g = r * N + node;
      int p0 = ptr[g], p1 = ptr[g + 1];
      EPair e;
      if (p0 < p1) e = pay[p0];
      for (int p = p0; p < p1; ++p) {
        EPair cur = e;
        if (p + 1 < p1) e = pay[p + 1];
        bf16x8 x = *reinterpret_cast<const bf16x8*>(Xbf + (size_t)cur.c * 256 + cl * 8);
#pragma unroll
        for (int j = 0; j < 8; ++j) acc[j] += cur.v * bf2f(x[j]);
      }
    }
    uint4 o;
    o.x = (unsigned)f2bf(acc[0]) | ((unsigned)f2bf(acc[1]) << 16);
    o.y = (unsigned)f2bf(acc[2]) | ((unsigned)f2bf(acc[3]) << 16);
    o.z = (unsigned)f2bf(acc[4]) | ((unsigned)f2bf(acc[5]) << 16);
    o.w = (unsigned)f2bf(acc[6]) | ((unsigned)f2bf(acc[7]) << 16);
    int boff = rr * 512 + cl * 16;
    boff ^= (rr & 7) << 4;              // XOR swizzle (matches reader)
    *reinterpret_cast<uint4*>(reinterpret_cast<char*>(lds) + boff) = o;
  }
}

// ---------------- fused layer 1 (+ layer-2 transform) ----------------
// 512 threads / 8 waves; 32-row tile; wave w owns cols [w*32, w*32+32) in L1 MFMA
__global__ __launch_bounds__(512, 8)
void fused_l1(const EPair* __restrict__ pay1, const int* __restrict__ ptr1,
              const unsigned short* __restrict__ Xbf,
              const unsigned short* __restrict__ W1p,
              const float* __restrict__ bias1,
              const unsigned short* __restrict__ W2p,
              unsigned short* __restrict__ Y2, int N) {
  __shared__ unsigned short tile[32 * 256];   // 16 KB
  char* lds = reinterpret_cast<char*>(tile);
  const int tid = threadIdx.x;
  const int w = tid >> 6, lane = tid & 63;
  const int unit = tid >> 5, cl = tid & 31;
  const int node0 = blockIdx.x * 32;

  f32x4 acc[2][2];
#pragma unroll
  for (int mi = 0; mi < 2; ++mi)
#pragma unroll
    for (int ni = 0; ni < 2; ++ni) acc[mi][ni] = (f32x4)(0.f);

  for (int r = 0; r < REFF; ++r) {
    gather_rows_bf(pay1, ptr1, Xbf, tile, node0, N, r, unit, cl);
    __syncthreads();
#pragma unroll 2
    for (int ks = 0; ks < 8; ++ks) {
      bf16x8 a[2];
#pragma unroll
      for (int mi = 0; mi < 2; ++mi) {
        int row = mi * 16 + (lane & 15);
        int boff = (row * 512 + ks * 64 + ((lane >> 4) << 4)) ^ ((row & 7) << 4);
        a[mi] = *reinterpret_cast<const bf16x8*>(lds + boff);
      }
#pragma unroll
      for (int ni = 0; ni < 2; ++ni) {
        int niG = w * 2 + ni;
        bf16x8 b = *reinterpret_cast<const bf16x8*>(
            W1p + (((size_t)(r * 8 + ks) * 16 + niG) << 9) + lane * 8);
#pragma unroll
        for (int mi = 0; mi < 2; ++mi)
          acc[mi][ni] = __builtin_amdgcn_mfma_f32_16x16x32_bf16(a[mi], b,
                                                               acc[mi][ni], 0, 0, 0);
      }
    }
    __syncthreads();
  }

  // epilogue: out1 tile = bf16(relu(acc + bias1)) -> LDS bf16 tile (same layout)
#pragma unroll
  for (int mi = 0; mi < 2; ++mi) {
#pragma unroll
    for (int ni = 0; ni < 2; ++ni) {
      int col = (w * 2 + ni) * 16 + (lane & 15);
      float bb = bias1[col];
#pragma unroll
      for (int reg = 0; reg < 4; ++reg) {
        int row = mi * 16 + ((lane >> 4) << 2) + reg;
        float v = fmaxf(acc[mi][ni][reg] + bb, 0.f);
        int b = (row * 512 + col * 2) ^ ((row & 7) << 4);
        *reinterpret_cast<unsigned short*>(lds + b) = f2bf(v);
      }
    }
  }
  __syncthreads();

  // layer-2 transform: Y2[r'] tile = out1_tile @ W2_{r'}; jobs j = (r', nj)
  for (int j = w; j < 18; j += 8) {
    int rp = j >> 1, nj = j & 1;
    f32x4 a2[2];
    a2[0] = (f32x4)(0.f); a2[1] = (f32x4)(0.f);
#pragma unroll
    for (int ks = 0; ks < 8; ++ks) {
      bf16x8 b = *reinterpret_cast<const bf16x8*>(
          W2p + (((size_t)(rp * 8 + ks) * 2 + nj) << 9) + lane * 8);
#pragma unroll
      for (int mi = 0; mi < 2; ++mi) {
        int row = mi * 16 + (lane & 15);
        int boff = (row * 512 + ks * 64 + ((lane >> 4) << 4)) ^ ((row & 7) << 4);
        bf16x8 a = *reinterpret_cast<const bf16x8*>(lds + boff);
        a2[mi] = __builtin_amdgcn_mfma_f32_16x16x32_bf16(a, b, a2[mi], 0, 0, 0);
      }
    }
    int col = nj * 16 + (lane & 15);
#pragma unroll
    for (int mi = 0; mi < 2; ++mi)
#pragma unroll
      for (int reg = 0; reg < 4; ++reg) {
        int row = node0 + mi * 16 + ((lane >> 4) << 2) + reg;
        if (row < N)
          Y2[((size_t)rp * N + row) * 32 + col] = f2bf(a2[mi][reg]);
      }
  }
}

// ---------------- layer 2 gather: wave per node, 4 edges in flight ----------------
__global__ __launch_bounds__(512, 8)
void gather_out_kernel(const EPair* __restrict__ pay2,
                       const int* __restrict__ ptr2,
                       const unsigned short* __restrict__ Y2,
                       const float* __restrict__ bias2,
                       float* __restrict__ out, int N) {
  int wv = threadIdx.x >> 6;
  int lane = threadIdx.x & 63;
  int qw = lane >> 4, c = lane & 15;
  int n = blockIdx.x * 8 + wv;
  if (n >= N) return;
  int p0 = ptr2[n], p1 = ptr2[n + 1];
  float ax = 0.f, ay = 0.f;
  for (int p = p0 + qw; p < p1; p += 4) {
    EPair cur = pay2[p];
    unsigned u = *reinterpret_cast<const unsigned*>(Y2 + (size_t)cur.c * 32 + c * 2);
    ax += cur.v * __uint_as_float(u << 16);
    ay += cur.v * __uint_as_float(u & 0xFFFF0000u);
  }
  ax += __shfl_xor(ax, 16); ay += __shfl_xor(ay, 16);
  ax += __shfl_xor(ax, 32); ay += __shfl_xor(ay, 32);
  if (lane < 16) {
    float2 o;
    o.x = ax + bias2[c * 2];
    o.y = ay + bias2[c * 2 + 1];
    reinterpret_cast<float2*>(out)[(size_t)n * 16 + c] = o;
  }
}

extern "C" void kernel_launch(void* const* d_in, const int* in_sizes, int n_in,
                              void* d_out, int out_size, void* d_ws, size_t ws_size,
                              hipStream_t stream) {
  const float* features = (const float*)d_in[0];
  const float* ver_vals = (const float*)d_in[1];
  const float* comps1   = (const float*)d_in[2];
  const float* bases1   = (const float*)d_in[3];
  const float* comps2   = (const float*)d_in[4];
  const float* bases2   = (const float*)d_in[5];
  const float* bias1    = (const float*)d_in[6];
  const float* bias2    = (const float*)d_in[7];
  const int* ver_rows   = (const int*)d_in[8];
  const int* ver_cols   = (const int*)d_in[9];

  const int N = in_sizes[0] / 256;   // 30000
  const int E = in_sizes[1];         // 500000
  const int NR = REFF * N;           // 270000
  const int NT1 = (NR + 1023) / 1024;
  const int NT2 = (N + 1023) / 1024;

  // ---- workspace layout (~44 MB; 64.1 MB proven-safe) ----
  char* p = (char*)d_ws;
  unsigned short* Xbf = (unsigned short*)p; p += (size_t)N * 256 * 2;        // 15.36 MB
  unsigned short* Y2  = (unsigned short*)p; p += (size_t)REFF * N * 32 * 2;  // 17.28 MB
  unsigned short* W1p = (unsigned short*)p; p += (size_t)REFF * 65536 * 2;   // 1.18 MB
  unsigned short* W2p = (unsigned short*)p; p += (size_t)REFF * 8192 * 2;    // 0.15 MB
  int* ptr1 = (int*)p;     p += (size_t)(NR + 4) * 4;
  int* ptr2 = (int*)p;     p += (size_t)(N + 4) * 4;
  EPair* pay1 = (EPair*)p; p += (size_t)E * 8;
  EPair* pay2 = (EPair*)p; p += (size_t)E * 8;
  int* deg1 = (int*)p;     p += (size_t)NR * 4;   // deg1+deg2 contiguous: one memset
  int* deg2 = (int*)p;     p += (size_t)N * 4;
  int* bsum1 = (int*)p;    p += 512 * 4;
  int* bsum2 = (int*)p;    p += 512 * 4;

  // ---- CSR build (both keys) ----
  hipMemsetAsync(deg1, 0, (size_t)(NR + N) * 4, stream);
  hist_both_kernel<<<(E + 255) / 256, 256, 0, stream>>>(ver_rows, deg1, deg2, E, N);
  scan1_both<<<NT1 + NT2, 256, 0, stream>>>(deg1, bsum1, NR, NT1, deg2, bsum2, N);
  scan2_both<<<2, 512, 0, stream>>>(bsum1, ptr1, NT1, NR, bsum2, ptr2, NT2, N);
  scan3_both<<<NT1 + NT2, 256, 0, stream>>>(deg1, bsum1, ptr1, NR, NT1,
                                            deg2, bsum2, ptr2, N);
  fill_both_kernel<<<(E + 255) / 256, 256, 0, stream>>>(
      ver_rows, ver_cols, ver_vals, deg1, ptr1, pay1, deg2, ptr2, pay2, E, N);

  // ---- prep: Xbf + packed weights (one launch) ----
  const int prep_total = N * 64 + REFF * 8 * 16 * 512 + REFF * 8 * 2 * 512;
  prep_kernel<<<(prep_total + 255) / 256, 256, 0, stream>>>(
      features, Xbf, comps1, bases1, W1p, comps2, bases2, W2p, N);

  // ---- fused layer 1 + layer-2 transform ----
  fused_l1<<<(N + 31) / 32, 512, 0, stream>>>(pay1, ptr1, Xbf, W1p, bias1,
                                              W2p, Y2, N);
  // ---- layer 2 gather ----
  gather_out_kernel<<<(N + 7) / 8, 512, 0, stream>>>(pay2, ptr2, Y2, bias2,
                                                     (float*)d_out, N);
}

// Round 9
// 229.795 us; speedup vs baseline: 4.1192x; 1.1317x over previous
//
#include <hip/hip_runtime.h>

typedef __attribute__((ext_vector_type(8))) short bf16x8;
typedef __attribute__((ext_vector_type(4))) float f32x4;

constexpr int NB = 16;    // bases
constexpr int REFF = 9;   // relations

struct alignas(8) EPair { float v; int c; };

__device__ __forceinline__ unsigned short f2bf(float f) {
  unsigned u = __float_as_uint(f);
  u += 0x7FFFu + ((u >> 16) & 1u);          // round-to-nearest-even
  return (unsigned short)(u >> 16);
}
__device__ __forceinline__ float bf2f(short s) {
  return __uint_as_float(((unsigned)(unsigned short)s) << 16);
}
__device__ __forceinline__ float bflo(unsigned u) {
  return __uint_as_float(u << 16);
}
__device__ __forceinline__ float bfhi(unsigned u) {
  return __uint_as_float(u & 0xFFFF0000u);
}

// ---------------- merged: histogram (CSR1 only) + prep (Xbf, W1p, W2p) ----------------
__device__ __forceinline__ unsigned short pack_w_one(const float* __restrict__ comps,
                                                     const float* __restrict__ bases,
                                                     int idx, int NTI, int NTOT) {
  int j = idx & 7;
  int lane = (idx >> 3) & 63;
  int ni = (idx >> 9) % NTI;
  int t = (idx >> 9) / NTI;        // r*8 + ks
  int ks = t & 7;
  int r = t >> 3;
  int k = ks * 32 + ((lane >> 4) << 3) + j;
  int n = ni * 16 + (lane & 15);
  float acc = 0.f;
#pragma unroll
  for (int b = 0; b < NB; ++b)
    acc += comps[r * NB + b] * bases[(size_t)b * 256 * NTOT + (size_t)k * NTOT + n];
  return f2bf(acc);
}

__global__ void hist_prep_kernel(const int* __restrict__ rows,
                                 int* __restrict__ deg1, int E,
                                 const float* __restrict__ features,
                                 unsigned short* __restrict__ Xbf,
                                 const float* __restrict__ comps1,
                                 const float* __restrict__ bases1,
                                 unsigned short* __restrict__ W1p,
                                 const float* __restrict__ comps2,
                                 const float* __restrict__ bases2,
                                 unsigned short* __restrict__ W2p, int N) {
  int idx = blockIdx.x * 256 + threadIdx.x;
  if (idx < E) atomicAdd(&deg1[rows[idx]], 1);
  const int n4 = N * 64;                 // float4 units of features
  const int PW1 = REFF * 8 * 16 * 512;   // 589824
  const int PW2 = REFF * 8 * 2 * 512;    // 73728
  if (idx < n4) {
    float4 f = reinterpret_cast<const float4*>(features)[idx];
    ushort4 o;
    o.x = f2bf(f.x); o.y = f2bf(f.y); o.z = f2bf(f.z); o.w = f2bf(f.w);
    reinterpret_cast<ushort4*>(Xbf)[idx] = o;
  } else if (idx < n4 + PW1) {
    int i = idx - n4;
    W1p[i] = pack_w_one(comps1, bases1, i, 16, 256);
  } else if (idx < n4 + PW1 + PW2) {
    int i = idx - n4 - PW1;
    W2p[i] = pack_w_one(comps2, bases2, i, 2, 32);
  }
}

// ---------------- scan over NR rows (R3-proven 3-pass) ----------------
__global__ void scan1_kernel(const int* __restrict__ deg, int* __restrict__ bsum,
                             int NR) {
  __shared__ int s[256];
  int t = threadIdx.x;
  int base = blockIdx.x * 1024 + t * 4;
  int acc = 0;
#pragma unroll
  for (int q = 0; q < 4; ++q)
    if (base + q < NR) acc += deg[base + q];
  s[t] = acc;
  __syncthreads();
  for (int off = 128; off > 0; off >>= 1) {
    if (t < off) s[t] += s[t + off];
    __syncthreads();
  }
  if (t == 0) bsum[blockIdx.x] = s[0];
}

__global__ void scan2_kernel(int* __restrict__ bsum, int* __restrict__ ptr,
                             int NT, int NR) {
  __shared__ int s[512];
  int t = threadIdx.x;
  int v = (t < NT) ? bsum[t] : 0;
  s[t] = v;
  __syncthreads();
  for (int off = 1; off < 512; off <<= 1) {
    int x = (t >= off) ? s[t - off] : 0;
    __syncthreads();
    s[t] += x;
    __syncthreads();
  }
  if (t < NT) bsum[t] = s[t] - v;          // exclusive
  if (t == NT - 1) ptr[NR] = s[t];
}

__global__ void scan3_kernel(const int* __restrict__ deg,
                             const int* __restrict__ bsum,
                             int* __restrict__ ptr, int NR) {
  __shared__ int s[256];
  int t = threadIdx.x;
  int base = blockIdx.x * 1024 + t * 4;
  int d[4];
#pragma unroll
  for (int q = 0; q < 4; ++q)
    d[q] = (base + q < NR) ? deg[base + q] : 0;
  int tsum = d[0] + d[1] + d[2] + d[3];
  s[t] = tsum;
  __syncthreads();
  for (int off = 1; off < 256; off <<= 1) {
    int x = (t >= off) ? s[t - off] : 0;
    __syncthreads();
    s[t] += x;
    __syncthreads();
  }
  int off0 = bsum[blockIdx.x] + s[t] - tsum;
#pragma unroll
  for (int q = 0; q < 4; ++q) {
    if (base + q < NR) ptr[base + q] = off0;
    off0 += d[q];
  }
}

__global__ void fill_kernel(const int* __restrict__ rows,
                            const int* __restrict__ cols,
                            const float* __restrict__ vals,
                            int* __restrict__ deg1, const int* __restrict__ ptr1,
                            EPair* __restrict__ pay1, int E) {
  int e = blockIdx.x * 256 + threadIdx.x;
  if (e >= E) return;
  int g = rows[e];
  int o1 = atomicSub(&deg1[g], 1);
  EPair pv; pv.v = vals[e]; pv.c = cols[e];
  pay1[ptr1[g] + o1 - 1] = pv;
}

// ---------------- gather: half-wave owns a whole row, 2-edge ILP ----------------
__device__ __forceinline__ void gather_rows_bf(const EPair* __restrict__ pay,
                                               const int* __restrict__ ptr,
                                               const unsigned short* __restrict__ Xbf,
                                               unsigned short* lds,
                                               int node0, int N, int r,
                                               int unit, int cl) {
#pragma unroll
  for (int q = 0; q < 2; ++q) {
    int rr = unit * 2 + q;              // row within 32-row tile
    int node = node0 + rr;
    float acc[8];
#pragma unroll
    for (int j = 0; j < 8; ++j) acc[j] = 0.f;
    if (node < N) {
      int g = r * N + node;
      int p0 = ptr[g], p1 = ptr[g + 1];
      int p = p0;
      for (; p + 2 <= p1; p += 2) {     // two edges in flight
        EPair e0 = pay[p];
        EPair e1 = pay[p + 1];
        bf16x8 x0 = *reinterpret_cast<const bf16x8*>(Xbf + (size_t)e0.c * 256 + cl * 8);
        bf16x8 x1 = *reinterpret_cast<const bf16x8*>(Xbf + (size_t)e1.c * 256 + cl * 8);
#pragma unroll
        for (int j = 0; j < 8; ++j)
          acc[j] += e0.v * bf2f(x0[j]) + e1.v * bf2f(x1[j]);
      }
      if (p < p1) {
        EPair e0 = pay[p];
        bf16x8 x0 = *reinterpret_cast<const bf16x8*>(Xbf + (size_t)e0.c * 256 + cl * 8);
#pragma unroll
        for (int j = 0; j < 8; ++j) acc[j] += e0.v * bf2f(x0[j]);
      }
    }
    uint4 o;
    o.x = (unsigned)f2bf(acc[0]) | ((unsigned)f2bf(acc[1]) << 16);
    o.y = (unsigned)f2bf(acc[2]) | ((unsigned)f2bf(acc[3]) << 16);
    o.z = (unsigned)f2bf(acc[4]) | ((unsigned)f2bf(acc[5]) << 16);
    o.w = (unsigned)f2bf(acc[6]) | ((unsigned)f2bf(acc[7]) << 16);
    int boff = rr * 512 + cl * 16;
    boff ^= (rr & 7) << 4;              // XOR swizzle (matches reader)
    *reinterpret_cast<uint4*>(reinterpret_cast<char*>(lds) + boff) = o;
  }
}

// ---------------- fused layer 1 + layer-2 transform ----------------
// 512 threads / 8 waves; 32-row tile; Y2 node-major [node][r][32]
__global__ __launch_bounds__(512, 8)
void fused_l1(const EPair* __restrict__ pay1, const int* __restrict__ ptr1,
              const unsigned short* __restrict__ Xbf,
              const unsigned short* __restrict__ W1p,
              const float* __restrict__ bias1,
              const unsigned short* __restrict__ W2p,
              unsigned short* __restrict__ Y2, int N) {
  __shared__ unsigned short tile[32 * 256];   // 16 KB
  char* lds = reinterpret_cast<char*>(tile);
  const int tid = threadIdx.x;
  const int w = tid >> 6, lane = tid & 63;
  const int unit = tid >> 5, cl = tid & 31;
  const int node0 = blockIdx.x * 32;

  f32x4 acc[2][2];
#pragma unroll
  for (int mi = 0; mi < 2; ++mi)
#pragma unroll
    for (int ni = 0; ni < 2; ++ni) acc[mi][ni] = (f32x4)(0.f);

  for (int r = 0; r < REFF; ++r) {
    gather_rows_bf(pay1, ptr1, Xbf, tile, node0, N, r, unit, cl);
    __syncthreads();
#pragma unroll 2
    for (int ks = 0; ks < 8; ++ks) {
      bf16x8 a[2];
#pragma unroll
      for (int mi = 0; mi < 2; ++mi) {
        int row = mi * 16 + (lane & 15);
        int boff = (row * 512 + ks * 64 + ((lane >> 4) << 4)) ^ ((row & 7) << 4);
        a[mi] = *reinterpret_cast<const bf16x8*>(lds + boff);
      }
#pragma unroll
      for (int ni = 0; ni < 2; ++ni) {
        int niG = w * 2 + ni;
        bf16x8 b = *reinterpret_cast<const bf16x8*>(
            W1p + (((size_t)(r * 8 + ks) * 16 + niG) << 9) + lane * 8);
#pragma unroll
        for (int mi = 0; mi < 2; ++mi)
          acc[mi][ni] = __builtin_amdgcn_mfma_f32_16x16x32_bf16(a[mi], b,
                                                               acc[mi][ni], 0, 0, 0);
      }
    }
    __syncthreads();
  }

  // epilogue: out1 tile = bf16(relu(acc + bias1)) -> LDS bf16 tile (same layout)
#pragma unroll
  for (int mi = 0; mi < 2; ++mi) {
#pragma unroll
    for (int ni = 0; ni < 2; ++ni) {
      int col = (w * 2 + ni) * 16 + (lane & 15);
      float bb = bias1[col];
#pragma unroll
      for (int reg = 0; reg < 4; ++reg) {
        int row = mi * 16 + ((lane >> 4) << 2) + reg;
        float v = fmaxf(acc[mi][ni][reg] + bb, 0.f);
        int b = (row * 512 + col * 2) ^ ((row & 7) << 4);
        *reinterpret_cast<unsigned short*>(lds + b) = f2bf(v);
      }
    }
  }
  __syncthreads();

  // layer-2 transform: wave w handles relation rp = w (wave 0 also rp=8), both nj
  for (int rp = w; rp < REFF; rp += 8) {
    f32x4 a2[2][2];   // [mi][nj]
#pragma unroll
    for (int mi = 0; mi < 2; ++mi) {
      a2[mi][0] = (f32x4)(0.f);
      a2[mi][1] = (f32x4)(0.f);
    }
#pragma unroll
    for (int ks = 0; ks < 8; ++ks) {
      bf16x8 b0 = *reinterpret_cast<const bf16x8*>(
          W2p + (((size_t)(rp * 8 + ks) * 2 + 0) << 9) + lane * 8);
      bf16x8 b1 = *reinterpret_cast<const bf16x8*>(
          W2p + (((size_t)(rp * 8 + ks) * 2 + 1) << 9) + lane * 8);
#pragma unroll
      for (int mi = 0; mi < 2; ++mi) {
        int row = mi * 16 + (lane & 15);
        int boff = (row * 512 + ks * 64 + ((lane >> 4) << 4)) ^ ((row & 7) << 4);
        bf16x8 a = *reinterpret_cast<const bf16x8*>(lds + boff);
        a2[mi][0] = __builtin_amdgcn_mfma_f32_16x16x32_bf16(a, b0, a2[mi][0], 0, 0, 0);
        a2[mi][1] = __builtin_amdgcn_mfma_f32_16x16x32_bf16(a, b1, a2[mi][1], 0, 0, 0);
      }
    }
    int c0 = lane & 15;
#pragma unroll
    for (int mi = 0; mi < 2; ++mi)
#pragma unroll
      for (int reg = 0; reg < 4; ++reg) {
        int row = node0 + mi * 16 + ((lane >> 4) << 2) + reg;
        if (row < N) {
          size_t base = (size_t)row * (REFF * 32) + rp * 32;
          Y2[base + c0] = f2bf(a2[mi][0][reg]);
          Y2[base + 16 + c0] = f2bf(a2[mi][1][reg]);
        }
      }
  }
}

// ---------------- layer 2 gather straight off CSR1: out[n] = bias2 + sum_r sum_e v*Y2[src][r] ----------------
// wave per node; quarter-wave qw handles relations r = qw, qw+4, qw+8; 2-edge ILP
__global__ __launch_bounds__(512, 8)
void gather_out_kernel(const EPair* __restrict__ pay1,
                       const int* __restrict__ ptr1,
                       const unsigned short* __restrict__ Y2,
                       const float* __restrict__ bias2,
                       float* __restrict__ out, int N) {
  int wv = threadIdx.x >> 6;
  int lane = threadIdx.x & 63;
  int qw = lane >> 4, c = lane & 15;
  int n = blockIdx.x * 8 + wv;
  if (n >= N) return;
  float ax = 0.f, ay = 0.f;
  for (int r = qw; r < REFF; r += 4) {
    int g = r * N + n;
    int p0 = ptr1[g], p1 = ptr1[g + 1];
    int p = p0;
    for (; p + 2 <= p1; p += 2) {
      EPair e0 = pay1[p];
      EPair e1 = pay1[p + 1];
      unsigned u0 = *reinterpret_cast<const unsigned*>(
          Y2 + (size_t)e0.c * (REFF * 32) + r * 32 + c * 2);
      unsigned u1 = *reinterpret_cast<const unsigned*>(
          Y2 + (size_t)e1.c * (REFF * 32) + r * 32 + c * 2);
      ax += e0.v * bflo(u0) + e1.v * bflo(u1);
      ay += e0.v * bfhi(u0) + e1.v * bfhi(u1);
    }
    if (p < p1) {
      EPair e0 = pay1[p];
      unsigned u0 = *reinterpret_cast<const unsigned*>(
          Y2 + (size_t)e0.c * (REFF * 32) + r * 32 + c * 2);
      ax += e0.v * bflo(u0);
      ay += e0.v * bfhi(u0);
    }
  }
  ax += __shfl_xor(ax, 16); ay += __shfl_xor(ay, 16);
  ax += __shfl_xor(ax, 32); ay += __shfl_xor(ay, 32);
  if (lane < 16) {
    float2 o;
    o.x = ax + bias2[c * 2];
    o.y = ay + bias2[c * 2 + 1];
    reinterpret_cast<float2*>(out)[(size_t)n * 16 + c] = o;
  }
}

extern "C" void kernel_launch(void* const* d_in, const int* in_sizes, int n_in,
                              void* d_out, int out_size, void* d_ws, size_t ws_size,
                              hipStream_t stream) {
  const float* features = (const float*)d_in[0];
  const float* ver_vals = (const float*)d_in[1];
  const float* comps1   = (const float*)d_in[2];
  const float* bases1   = (const float*)d_in[3];
  const float* comps2   = (const float*)d_in[4];
  const float* bases2   = (const float*)d_in[5];
  const float* bias1    = (const float*)d_in[6];
  const float* bias2    = (const float*)d_in[7];
  const int* ver_rows   = (const int*)d_in[8];
  const int* ver_cols   = (const int*)d_in[9];

  const int N = in_sizes[0] / 256;   // 30000
  const int E = in_sizes[1];         // 500000
  const int NR = REFF * N;           // 270000
  const int NT = (NR + 1023) / 1024; // 264

  // ---- workspace layout (~40 MB; 64.1 MB proven-safe) ----
  char* p = (char*)d_ws;
  unsigned short* Xbf = (unsigned short*)p; p += (size_t)N * 256 * 2;        // 15.36 MB
  unsigned short* Y2  = (unsigned short*)p; p += (size_t)N * REFF * 32 * 2;  // 17.28 MB
  unsigned short* W1p = (unsigned short*)p; p += (size_t)REFF * 65536 * 2;   // 1.18 MB
  unsigned short* W2p = (unsigned short*)p; p += (size_t)REFF * 8192 * 2;    // 0.15 MB
  int* ptr1 = (int*)p;     p += (size_t)(NR + 4) * 4;
  EPair* pay1 = (EPair*)p; p += (size_t)E * 8;
  int* deg1 = (int*)p;     p += (size_t)NR * 4;
  int* bsum = (int*)p;     p += 512 * 4;

  // ---- CSR build + prep ----
  hipMemsetAsync(deg1, 0, (size_t)NR * 4, stream);
  const int prep_total = N * 64 + REFF * 8 * 16 * 512 + REFF * 8 * 2 * 512;
  const int hp_grid = ((prep_total > E ? prep_total : E) + 255) / 256;
  hist_prep_kernel<<<hp_grid, 256, 0, stream>>>(ver_rows, deg1, E,
                                                features, Xbf,
                                                comps1, bases1, W1p,
                                                comps2, bases2, W2p, N);
  scan1_kernel<<<NT, 256, 0, stream>>>(deg1, bsum, NR);
  scan2_kernel<<<1, 512, 0, stream>>>(bsum, ptr1, NT, NR);
  scan3_kernel<<<NT, 256, 0, stream>>>(deg1, bsum, ptr1, NR);
  fill_kernel<<<(E + 255) / 256, 256, 0, stream>>>(ver_rows, ver_cols, ver_vals,
                                                   deg1, ptr1, pay1, E);

  // ---- fused layer 1 + layer-2 transform ----
  fused_l1<<<(N + 31) / 32, 512, 0, stream>>>(pay1, ptr1, Xbf, W1p, bias1,
                                              W2p, Y2, N);
  // ---- layer 2 gather ----
  gather_out_kernel<<<(N + 7) / 8, 512, 0, stream>>>(pay1, ptr1, Y2, bias2,
                                                     (float*)d_out, N);
}